// Round 12
// baseline (36.073 us; speedup 1.0000x reference)
//
#include <hip/hip_runtime.h>
#include <math.h>

#define B_ 8
#define M_ 10
#define S_ 200
#define PADS_ 208            // S padded to multiple of 16 (sentinel points)
#define N_ 2048
#define L_ 128
#define BETA_ 0.01f
#define EPS_ 1e-6f
#define INF_U 0x7F7F7F7Fu
#define SENT_ 5.0e18f        // sentinel coord; |p|^2 = 7.5e37, finite, never wins min

#define NT_ 128                            // n per block (proven shape)
#define TILES_ (N_ / NT_)                  // 16
#define DIST_BLOCKS (B_ * M_ * TILES_)     // 1280
#define VS_BLOCKS ((B_ * N_) / 256)        // 64
#define MID_BLOCKS (VS_BLOCKS + B_*M_ + 1) // 145

// DPP 16-lane (row) min-reduction step — VALU pipe, no DS ops.
#define DPPMIN_(v, ctrl) \
    v = fminf(v, __int_as_float(__builtin_amdgcn_mov_dpp(__float_as_int(v), ctrl, 0xf, 0xf, true)))

// xor-32 min via v_permlane32_swap (VALU pipe; replaces a DS shfl).
// With A=B=v: result lanes i<32 get {v[i], v[i+32]}, i>=32 get {v[i-32], v[i]}.
__device__ __forceinline__ float permlane32_min_(float v) {
    int a = __float_as_int(v);
    auto r = __builtin_amdgcn_permlane32_swap(a, a, false, false);
    return fminf(__int_as_float(r[0]), __int_as_float(r[1]));
}

__device__ __forceinline__ float fexp_(float x, float p) {
    float s = (x > 0.f) ? 1.f : ((x < 0.f) ? -1.f : 0.f);
    return s * __powf(fmaxf(fabsf(x), EPS_), p);   // base > 0 -> fast pow safe
}

// ---------------------------------------------------------------------------
// dist_k: block = (bm, 128-n tile). 1280 blocks x 256; __launch_bounds__(.,5)
// pins VGPR <= ~102 so all 5 blocks/CU stay co-resident (20 waves/CU).
//   In-block staging (fast trig): R, pts[208] w/ |p|^2, rotated n as
//   (A=-2X, |X|^2).
//   Thread: sg=lane&15 owns 13 s (k*16+sg); ng=wave*4+(lane>>4) owns 8 n.
//   Inner loop: 1 ds_read_b128 + 8 evals (add+3fma+min) + 7-min tree.
//   smin reduce: xor16 = shfl (DS), xor32 = permlane32_swap (VALU),
//   then 16-lane conflict-free LDS atomicMin per k.
//   V epilogue: DPP row butterfly (VALU); row leaders store 8 consecutive
//   V floats straight to vpart (2x float4).
//   Outputs: pure stores. Block 0 zeroes out[] (mid_k accumulates into it).
// ---------------------------------------------------------------------------
__global__ __launch_bounds__(256, 5) void dist_k(
    const float* __restrict__ ipts,  const float* __restrict__ trans,
    const float* __restrict__ rot,   const float* __restrict__ psize,
    const float* __restrict__ shp,   const float* __restrict__ def,
    const float* __restrict__ etas,  const float* __restrict__ omegas,
    float* __restrict__ vpart, float* __restrict__ spart,
    float* __restrict__ out)
{
    __shared__ float4 sPts[PADS_];          // 3328 B
    __shared__ float4 sXt[NT_];             // 2048 B  (A0,A1,A2,c2)
    __shared__ unsigned int sMinS[PADS_];   // 832 B
    __shared__ float sR[9];

    const int t    = threadIdx.x;
    const int tile = blockIdx.x % TILES_;
    const int bm   = blockIdx.x / TILES_;
    const int b    = bm / M_;
    const int lane = t & 63, wave = t >> 6;

    if (blockIdx.x == 0 && t < 4) out[t] = 0.f;   // mid_k accumulates into out

    if (t == 0) {
        float w = rot[bm*4+0], x = rot[bm*4+1], y = rot[bm*4+2], z = rot[bm*4+3];
        float inv = 1.f / sqrtf(w*w + x*x + y*y + z*z);
        w *= inv; x *= inv; y *= inv; z *= inv;
        sR[0] = 1.f - 2.f*(y*y + z*z); sR[1] = 2.f*(x*y - w*z);       sR[2] = 2.f*(x*z + w*y);
        sR[3] = 2.f*(x*y + w*z);       sR[4] = 1.f - 2.f*(x*x + z*z); sR[5] = 2.f*(y*z - w*x);
        sR[6] = 2.f*(x*z - w*y);       sR[7] = 2.f*(y*z + w*x);       sR[8] = 1.f - 2.f*(x*x + y*y);
    }
    if (t < PADS_) {
        sMinS[t] = INF_U;
        if (t < S_) {
            float a1 = psize[bm*3+0], a2 = psize[bm*3+1], a3 = psize[bm*3+2];
            float e1 = shp[bm*2+0],  e2 = shp[bm*2+1];
            float d0 = def[bm*2+0],  d1 = def[bm*2+1];
            float eta = etas[bm*S_+t], om = omegas[bm*S_+t];
            float ce = __cosf(eta), se = __sinf(eta);
            float co = __cosf(om),  so = __sinf(om);
            float fce = fexp_(ce, e1), fse = fexp_(se, e1);
            float fco = fexp_(co, e2), fso = fexp_(so, e2);
            float px = a1 * fce * fco;
            float py = a2 * fce * fso;
            float pz = a3 * fse;
            float fr = pz / a3;
            px *= d0*fr + 1.f;
            py *= d1*fr + 1.f;
            sPts[t] = make_float4(px, py, pz, px*px + py*py + pz*pz);
        } else {
            sPts[t] = make_float4(SENT_, SENT_, SENT_, 3.f*SENT_*SENT_);
        }
    }
    __syncthreads();

    if (t < NT_) {
        int n = tile*NT_ + t;
        const float* ip = ipts + (size_t)(b*N_ + n)*3;
        float cx = ip[0] - trans[bm*3+0];
        float cy = ip[1] - trans[bm*3+1];
        float cz = ip[2] - trans[bm*3+2];
        float X0 = sR[0]*cx + sR[1]*cy + sR[2]*cz;
        float X1 = sR[3]*cx + sR[4]*cy + sR[5]*cz;
        float X2 = sR[6]*cx + sR[7]*cy + sR[8]*cz;
        sXt[t] = make_float4(-2.f*X0, -2.f*X1, -2.f*X2, X0*X0 + X1*X1 + X2*X2);
    }
    __syncthreads();

    const int sg = lane & 15;                // s-group (lane bits 0..3)
    const int ng = wave*4 + (lane >> 4);     // n-group 0..15, owns n = ng*8+j

    float4 A[8];
    #pragma unroll
    for (int j = 0; j < 8; ++j) A[j] = sXt[ng*8 + j];   // broadcast reads

    float vmin[8];
    #pragma unroll
    for (int j = 0; j < 8; ++j) vmin[j] = 3.4e38f;

    float sm[13];                            // smin partials, register-resident

    #pragma unroll
    for (int k = 0; k < 13; ++k) {
        float4 p = sPts[k*16 + sg];          // 2-way bank alias = free
        float d[8];
        #pragma unroll
        for (int j = 0; j < 8; ++j) {
            d[j] = fmaf(p.x, A[j].x,
                   fmaf(p.y, A[j].y,
                   fmaf(p.z, A[j].z, p.w + A[j].w)));
            vmin[j] = fminf(vmin[j], d[j]);
        }
        #pragma unroll
        for (int st = 4; st >= 1; st >>= 1)
            #pragma unroll
            for (int j = 0; j < st; ++j)
                d[j] = fminf(d[j], d[j + st]);
        sm[k] = d[0];
    }

    // smin: reduce over the 16 n-groups: xor16 = shfl (DS), xor32 = permlane
    // (VALU), then one conflict-free 16-lane LDS atomic per k.
    #pragma unroll
    for (int k = 0; k < 13; ++k) {
        float v = sm[k];
        v = fminf(v, __shfl_xor(v, 16));
        v = permlane32_min_(v);
        if (lane < 16) atomicMin(&sMinS[k*16 + sg], __float_as_uint(v));
    }

    // V: min over the 16 s-groups = DPP row butterfly (VALU pipe, no DS)
    #pragma unroll
    for (int j = 0; j < 8; ++j) {
        float v = vmin[j];
        DPPMIN_(v, 0xB1);   // quad_perm [1,0,3,2]  : xor1
        DPPMIN_(v, 0x4E);   // quad_perm [2,3,0,1]  : xor2
        DPPMIN_(v, 0x141);  // row_half_mirror
        DPPMIN_(v, 0x140);  // row_mirror
        vmin[j] = v;
    }
    if (sg == 0) {                            // row leaders: 8 consecutive V
        float* vp = vpart + bm*N_ + tile*NT_ + ng*8;
        *reinterpret_cast<float4*>(vp)     = make_float4(vmin[0], vmin[1], vmin[2], vmin[3]);
        *reinterpret_cast<float4*>(vp + 4) = make_float4(vmin[4], vmin[5], vmin[6], vmin[7]);
    }

    __syncthreads();                          // sMinS complete
    if (t < S_) spart[(size_t)(bm*TILES_ + tile)*S_ + t] = __uint_as_float(sMinS[t]);
}

// ---------------------------------------------------------------------------
// mid_k: 145 blocks, three roles; all inputs crossed a dispatch boundary.
// Accumulates pre-scaled partials straight into out[] via atomicAdd:
//   bid < 64:          vsort -> out[0], out[1]
//   64 <= bid < 144:   dmp   -> out[0], out[1]
//   bid == 144:        KLD   -> out[0], out[3]
// ---------------------------------------------------------------------------
__global__ __launch_bounds__(256) void mid_k(const float* __restrict__ vpart,
                                             const float* __restrict__ spart,
                                             const float* __restrict__ probs,
                                             const float* __restrict__ mu,
                                             const float* __restrict__ logvar,
                                             float* __restrict__ out)
{
    __shared__ float sSum[4];
    int t = threadIdx.x, lane = t & 63, wave = t >> 6;

    if (blockIdx.x < VS_BLOCKS) {
        int g = blockIdx.x*256 + t;        // 0..B*N-1
        int b = g / N_, n = g % N_;
        float V[M_], P[M_];
        #pragma unroll
        for (int m = 0; m < M_; ++m) {
            V[m] = vpart[(b*M_ + m)*N_ + n];
            P[m] = probs[b*M_ + m];
        }
        #pragma unroll
        for (int i = 0; i < M_-1; ++i)
            #pragma unroll
            for (int j = 0; j < M_-1-i; ++j)
                if (V[j] > V[j+1]) {
                    float tv = V[j]; V[j] = V[j+1]; V[j+1] = tv;
                    float tp = P[j]; P[j] = P[j+1]; P[j+1] = tp;
                }
        float cum = 1.f, sum = 0.f;
        #pragma unroll
        for (int i = 0; i < M_; ++i) { sum += P[i] * cum * V[i]; cum *= (1.f - P[i]); }

        #pragma unroll
        for (int o = 1; o < 64; o <<= 1) sum += __shfl_xor(sum, o);
        if (lane == 0) sSum[wave] = sum;
        __syncthreads();
        if (t == 0) {
            float v = (sSum[0] + sSum[1] + sSum[2] + sSum[3]) / (float)(B_ * N_);
            atomicAdd(&out[0], v);
            atomicAdd(&out[1], v);
        }
    } else if (blockIdx.x < VS_BLOCKS + B_*M_) {
        int bm = blockIdx.x - VS_BLOCKS;   // 0..79
        float v = 0.f;
        if (t < S_) {
            const float* sp = spart + (size_t)bm*TILES_*S_ + t;
            float mn = 3.4e38f;
            #pragma unroll
            for (int tl = 0; tl < TILES_; ++tl) mn = fminf(mn, sp[tl*S_]);
            v = mn;
        }
        #pragma unroll
        for (int o = 1; o < 64; o <<= 1) v += __shfl_xor(v, o);
        if (lane == 0) sSum[wave] = v;
        __syncthreads();
        if (t == 0) {
            float s = (sSum[0] + sSum[1] + sSum[2] + sSum[3]) * probs[bm]
                      / (float)(B_ * S_);
            atomicAdd(&out[0], s);
            atomicAdd(&out[1], s);
        }
    } else {
        float s2 = 0.f;
        for (int i = t; i < B_*L_; i += 256) {
            float muv = mu[i], lv = logvar[i];
            s2 += -0.5f * (1.f + lv - muv*muv - expf(lv));
        }
        #pragma unroll
        for (int o = 1; o < 64; o <<= 1) s2 += __shfl_xor(s2, o);
        if (lane == 0) sSum[wave] = s2;
        __syncthreads();
        if (t == 0) {
            float kld = (sSum[0] + sSum[1] + sSum[2] + sSum[3]) / (float)B_;
            atomicAdd(&out[0], BETA_ * kld);
            atomicAdd(&out[3], kld);
            // out[2] (regs) stays 0 from dist_k's zeroing
        }
    }
}

extern "C" void kernel_launch(void* const* d_in, const int* in_sizes, int n_in,
                              void* d_out, int out_size, void* d_ws, size_t ws_size,
                              hipStream_t stream) {
    const float* ipts    = (const float*)d_in[0];
    const float* trans   = (const float*)d_in[1];
    const float* rot     = (const float*)d_in[2];
    const float* psize   = (const float*)d_in[3];
    const float* shp     = (const float*)d_in[4];
    const float* def     = (const float*)d_in[5];
    const float* probs   = (const float*)d_in[6];
    const float* etas    = (const float*)d_in[7];
    const float* omegas  = (const float*)d_in[8];
    const float* mu      = (const float*)d_in[9];
    const float* logvar  = (const float*)d_in[10];
    float* out = (float*)d_out;

    char* ws = (char*)d_ws;
    float* vpart = (float*)(ws);             // B*M*N*4        = 655360 B
    float* spart = (float*)(ws + 655360);    // B*M*TILES*S*4  = 1024000 B
    // all ws buffers fully written before read (pure stores + dispatch
    // boundary) -> no init needed. out zeroed by dist_k each call.

    dist_k<<<DIST_BLOCKS, 256, 0, stream>>>(ipts, trans, rot, psize, shp, def,
                                            etas, omegas, vpart, spart, out);
    mid_k<<<MID_BLOCKS, 256, 0, stream>>>(vpart, spart, probs, mu, logvar, out);
}

// Round 13
// 25.347 us; speedup vs baseline: 1.4231x; 1.4231x over previous
//
#include <hip/hip_runtime.h>
#include <math.h>

#define B_ 8
#define M_ 10
#define S_ 200
#define PADS_ 208            // S padded to multiple of 16 (sentinel points)
#define N_ 2048
#define L_ 128
#define BETA_ 0.01f
#define EPS_ 1e-6f
#define INF_U 0x7F7F7F7Fu
#define SENT_ 5.0e18f        // sentinel coord; |p|^2 = 7.5e37, finite, never wins min

#define NT_ 128                            // n per block (proven shape)
#define TILES_ (N_ / NT_)                  // 16
#define DIST_BLOCKS (B_ * M_ * TILES_)     // 1280
#define VS_BLOCKS ((B_ * N_) / 256)        // 64
#define MID_BLOCKS (VS_BLOCKS + B_*M_ + 1) // 145

// DPP 16-lane (row) min-reduction step — VALU pipe, no DS ops.
#define DPPMIN_(v, ctrl) \
    v = fminf(v, __int_as_float(__builtin_amdgcn_mov_dpp(__float_as_int(v), ctrl, 0xf, 0xf, true)))

__device__ __forceinline__ float fexp_(float x, float p) {
    float s = (x > 0.f) ? 1.f : ((x < 0.f) ? -1.f : 0.f);
    return s * __powf(fmaxf(fabsf(x), EPS_), p);   // base > 0 -> fast pow safe
}

// ---------------------------------------------------------------------------
// dist_k: block = (bm, 128-n tile). 1280 blocks x 256 (natural occupancy,
// ~100 VGPR, 4-5 blocks/CU — NO launch_bounds second arg: R12 showed it
// forces spill-to-scratch, VGPR 48 + 90 MB scratch traffic, 45 us).
//   In-block staging (fast trig): R, pts[208] w/ |p|^2, rotated n as
//   (A=-2X, |X|^2).
//   Thread: sg=lane&15 owns 13 s (k*16+sg); ng=wave*4+(lane>>4) owns 8 n.
//   Inner loop: 1 ds_read_b128 + 8 evals (add+3fma+min) + 7-min tree; smin
//   partial sm[k] register-resident (compile-time indices).
//   Post-loop: smin reduce = 2 shfl + 1 conflict-free masked LDS atomic per k.
//   V epilogue: DPP row butterfly (VALU); row leaders store 8 consecutive
//   V floats straight to vpart (2x float4).
//   Outputs: pure stores. Block 0 zeroes out[] (mid_k accumulates into it).
// ---------------------------------------------------------------------------
__global__ __launch_bounds__(256) void dist_k(
    const float* __restrict__ ipts,  const float* __restrict__ trans,
    const float* __restrict__ rot,   const float* __restrict__ psize,
    const float* __restrict__ shp,   const float* __restrict__ def,
    const float* __restrict__ etas,  const float* __restrict__ omegas,
    float* __restrict__ vpart, float* __restrict__ spart,
    float* __restrict__ out)
{
    __shared__ float4 sPts[PADS_];          // 3328 B
    __shared__ float4 sXt[NT_];             // 2048 B  (A0,A1,A2,c2)
    __shared__ unsigned int sMinS[PADS_];   // 832 B
    __shared__ float sR[9];

    const int t    = threadIdx.x;
    const int tile = blockIdx.x % TILES_;
    const int bm   = blockIdx.x / TILES_;
    const int b    = bm / M_;
    const int lane = t & 63, wave = t >> 6;

    if (blockIdx.x == 0 && t < 4) out[t] = 0.f;   // mid_k accumulates into out

    if (t == 0) {
        float w = rot[bm*4+0], x = rot[bm*4+1], y = rot[bm*4+2], z = rot[bm*4+3];
        float inv = 1.f / sqrtf(w*w + x*x + y*y + z*z);
        w *= inv; x *= inv; y *= inv; z *= inv;
        sR[0] = 1.f - 2.f*(y*y + z*z); sR[1] = 2.f*(x*y - w*z);       sR[2] = 2.f*(x*z + w*y);
        sR[3] = 2.f*(x*y + w*z);       sR[4] = 1.f - 2.f*(x*x + z*z); sR[5] = 2.f*(y*z - w*x);
        sR[6] = 2.f*(x*z - w*y);       sR[7] = 2.f*(y*z + w*x);       sR[8] = 1.f - 2.f*(x*x + y*y);
    }
    if (t < PADS_) {
        sMinS[t] = INF_U;
        if (t < S_) {
            float a1 = psize[bm*3+0], a2 = psize[bm*3+1], a3 = psize[bm*3+2];
            float e1 = shp[bm*2+0],  e2 = shp[bm*2+1];
            float d0 = def[bm*2+0],  d1 = def[bm*2+1];
            float eta = etas[bm*S_+t], om = omegas[bm*S_+t];
            float ce = __cosf(eta), se = __sinf(eta);
            float co = __cosf(om),  so = __sinf(om);
            float fce = fexp_(ce, e1), fse = fexp_(se, e1);
            float fco = fexp_(co, e2), fso = fexp_(so, e2);
            float px = a1 * fce * fco;
            float py = a2 * fce * fso;
            float pz = a3 * fse;
            float fr = pz / a3;
            px *= d0*fr + 1.f;
            py *= d1*fr + 1.f;
            sPts[t] = make_float4(px, py, pz, px*px + py*py + pz*pz);
        } else {
            sPts[t] = make_float4(SENT_, SENT_, SENT_, 3.f*SENT_*SENT_);
        }
    }
    __syncthreads();

    if (t < NT_) {
        int n = tile*NT_ + t;
        const float* ip = ipts + (size_t)(b*N_ + n)*3;
        float cx = ip[0] - trans[bm*3+0];
        float cy = ip[1] - trans[bm*3+1];
        float cz = ip[2] - trans[bm*3+2];
        float X0 = sR[0]*cx + sR[1]*cy + sR[2]*cz;
        float X1 = sR[3]*cx + sR[4]*cy + sR[5]*cz;
        float X2 = sR[6]*cx + sR[7]*cy + sR[8]*cz;
        sXt[t] = make_float4(-2.f*X0, -2.f*X1, -2.f*X2, X0*X0 + X1*X1 + X2*X2);
    }
    __syncthreads();

    const int sg = lane & 15;                // s-group (lane bits 0..3)
    const int ng = wave*4 + (lane >> 4);     // n-group 0..15, owns n = ng*8+j

    float4 A[8];
    #pragma unroll
    for (int j = 0; j < 8; ++j) A[j] = sXt[ng*8 + j];   // broadcast reads

    float vmin[8];
    #pragma unroll
    for (int j = 0; j < 8; ++j) vmin[j] = 3.4e38f;

    float sm[13];                            // smin partials, register-resident

    #pragma unroll
    for (int k = 0; k < 13; ++k) {
        float4 p = sPts[k*16 + sg];          // 2-way bank alias = free
        float d[8];
        #pragma unroll
        for (int j = 0; j < 8; ++j) {
            d[j] = fmaf(p.x, A[j].x,
                   fmaf(p.y, A[j].y,
                   fmaf(p.z, A[j].z, p.w + A[j].w)));
            vmin[j] = fminf(vmin[j], d[j]);
        }
        #pragma unroll
        for (int st = 4; st >= 1; st >>= 1)
            #pragma unroll
            for (int j = 0; j < st; ++j)
                d[j] = fminf(d[j], d[j + st]);
        sm[k] = d[0];
    }

    // smin: reduce over the 16 n-groups (lane bits 4,5 in-wave; waves via LDS)
    #pragma unroll
    for (int k = 0; k < 13; ++k) {
        float v = sm[k];
        v = fminf(v, __shfl_xor(v, 16));
        v = fminf(v, __shfl_xor(v, 32));
        if (lane < 16) atomicMin(&sMinS[k*16 + sg], __float_as_uint(v));
    }

    // V: min over the 16 s-groups = DPP row butterfly (VALU pipe, no DS)
    #pragma unroll
    for (int j = 0; j < 8; ++j) {
        float v = vmin[j];
        DPPMIN_(v, 0xB1);   // quad_perm [1,0,3,2]  : xor1
        DPPMIN_(v, 0x4E);   // quad_perm [2,3,0,1]  : xor2
        DPPMIN_(v, 0x141);  // row_half_mirror
        DPPMIN_(v, 0x140);  // row_mirror
        vmin[j] = v;
    }
    if (sg == 0) {                            // row leaders: 8 consecutive V
        float* vp = vpart + bm*N_ + tile*NT_ + ng*8;
        *reinterpret_cast<float4*>(vp)     = make_float4(vmin[0], vmin[1], vmin[2], vmin[3]);
        *reinterpret_cast<float4*>(vp + 4) = make_float4(vmin[4], vmin[5], vmin[6], vmin[7]);
    }

    __syncthreads();                          // sMinS complete
    if (t < S_) spart[(size_t)(bm*TILES_ + tile)*S_ + t] = __uint_as_float(sMinS[t]);
}

// ---------------------------------------------------------------------------
// mid_k: 145 blocks, three roles; all inputs crossed a dispatch boundary.
// Accumulates pre-scaled partials straight into out[] via atomicAdd:
//   bid < 64:          vsort -> out[0], out[1]
//   64 <= bid < 144:   dmp   -> out[0], out[1]
//   bid == 144:        KLD   -> out[0], out[3]
// ---------------------------------------------------------------------------
__global__ __launch_bounds__(256) void mid_k(const float* __restrict__ vpart,
                                             const float* __restrict__ spart,
                                             const float* __restrict__ probs,
                                             const float* __restrict__ mu,
                                             const float* __restrict__ logvar,
                                             float* __restrict__ out)
{
    __shared__ float sSum[4];
    int t = threadIdx.x, lane = t & 63, wave = t >> 6;

    if (blockIdx.x < VS_BLOCKS) {
        int g = blockIdx.x*256 + t;        // 0..B*N-1
        int b = g / N_, n = g % N_;
        float V[M_], P[M_];
        #pragma unroll
        for (int m = 0; m < M_; ++m) {
            V[m] = vpart[(b*M_ + m)*N_ + n];
            P[m] = probs[b*M_ + m];
        }
        #pragma unroll
        for (int i = 0; i < M_-1; ++i)
            #pragma unroll
            for (int j = 0; j < M_-1-i; ++j)
                if (V[j] > V[j+1]) {
                    float tv = V[j]; V[j] = V[j+1]; V[j+1] = tv;
                    float tp = P[j]; P[j] = P[j+1]; P[j+1] = tp;
                }
        float cum = 1.f, sum = 0.f;
        #pragma unroll
        for (int i = 0; i < M_; ++i) { sum += P[i] * cum * V[i]; cum *= (1.f - P[i]); }

        #pragma unroll
        for (int o = 1; o < 64; o <<= 1) sum += __shfl_xor(sum, o);
        if (lane == 0) sSum[wave] = sum;
        __syncthreads();
        if (t == 0) {
            float v = (sSum[0] + sSum[1] + sSum[2] + sSum[3]) / (float)(B_ * N_);
            atomicAdd(&out[0], v);
            atomicAdd(&out[1], v);
        }
    } else if (blockIdx.x < VS_BLOCKS + B_*M_) {
        int bm = blockIdx.x - VS_BLOCKS;   // 0..79
        float v = 0.f;
        if (t < S_) {
            const float* sp = spart + (size_t)bm*TILES_*S_ + t;
            float mn = 3.4e38f;
            #pragma unroll
            for (int tl = 0; tl < TILES_; ++tl) mn = fminf(mn, sp[tl*S_]);
            v = mn;
        }
        #pragma unroll
        for (int o = 1; o < 64; o <<= 1) v += __shfl_xor(v, o);
        if (lane == 0) sSum[wave] = v;
        __syncthreads();
        if (t == 0) {
            float s = (sSum[0] + sSum[1] + sSum[2] + sSum[3]) * probs[bm]
                      / (float)(B_ * S_);
            atomicAdd(&out[0], s);
            atomicAdd(&out[1], s);
        }
    } else {
        float s2 = 0.f;
        for (int i = t; i < B_*L_; i += 256) {
            float muv = mu[i], lv = logvar[i];
            s2 += -0.5f * (1.f + lv - muv*muv - expf(lv));
        }
        #pragma unroll
        for (int o = 1; o < 64; o <<= 1) s2 += __shfl_xor(s2, o);
        if (lane == 0) sSum[wave] = s2;
        __syncthreads();
        if (t == 0) {
            float kld = (sSum[0] + sSum[1] + sSum[2] + sSum[3]) / (float)B_;
            atomicAdd(&out[0], BETA_ * kld);
            atomicAdd(&out[3], kld);
            // out[2] (regs) stays 0 from dist_k's zeroing
        }
    }
}

extern "C" void kernel_launch(void* const* d_in, const int* in_sizes, int n_in,
                              void* d_out, int out_size, void* d_ws, size_t ws_size,
                              hipStream_t stream) {
    const float* ipts    = (const float*)d_in[0];
    const float* trans   = (const float*)d_in[1];
    const float* rot     = (const float*)d_in[2];
    const float* psize   = (const float*)d_in[3];
    const float* shp     = (const float*)d_in[4];
    const float* def     = (const float*)d_in[5];
    const float* probs   = (const float*)d_in[6];
    const float* etas    = (const float*)d_in[7];
    const float* omegas  = (const float*)d_in[8];
    const float* mu      = (const float*)d_in[9];
    const float* logvar  = (const float*)d_in[10];
    float* out = (float*)d_out;

    char* ws = (char*)d_ws;
    float* vpart = (float*)(ws);             // B*M*N*4        = 655360 B
    float* spart = (float*)(ws + 655360);    // B*M*TILES*S*4  = 1024000 B
    // all ws buffers fully written before read (pure stores + dispatch
    // boundary) -> no init needed. out zeroed by dist_k each call.

    dist_k<<<DIST_BLOCKS, 256, 0, stream>>>(ipts, trans, rot, psize, shp, def,
                                            etas, omegas, vpart, spart, out);
    mid_k<<<MID_BLOCKS, 256, 0, stream>>>(vpart, spart, probs, mu, logvar, out);
}

// Round 14
// 25.107 us; speedup vs baseline: 1.4368x; 1.0096x over previous
//
#include <hip/hip_runtime.h>
#include <math.h>

#define B_ 8
#define M_ 10
#define S_ 200
#define PADS_ 208            // S padded to multiple of 16 (sentinel points)
#define N_ 2048
#define L_ 128
#define BETA_ 0.01f
#define EPS_ 1e-6f
#define INF_U 0x7F7F7F7Fu
#define SENT_ 5.0e18f        // sentinel coord; |p|^2 = 7.5e37, finite, never wins min

#define NT_ 128                            // n per block (proven shape)
#define TILES_ (N_ / NT_)                  // 16
#define DIST_BLOCKS (B_ * M_ * TILES_)     // 1280
#define VS_BLOCKS ((B_ * N_) / 256)        // 64
#define MID_BLOCKS (VS_BLOCKS + B_*M_ + 1) // 145

// DPP 16-lane (row) min-reduction step — VALU pipe, no DS ops.
#define DPPMIN_(v, ctrl) \
    v = fminf(v, __int_as_float(__builtin_amdgcn_mov_dpp(__float_as_int(v), ctrl, 0xf, 0xf, true)))

// xor-16 min via v_permlane16_swap (VALU; replaces DS shfl_xor(16)).
// With A=B=v the two returned halves are v[i] and v[i^16].
__device__ __forceinline__ float permlane16_min_(float v) {
    int a = __float_as_int(v);
    auto r = __builtin_amdgcn_permlane16_swap(a, a, false, false);
    return fminf(__int_as_float(r[0]), __int_as_float(r[1]));
}
// xor-32 min via v_permlane32_swap (VALU; replaces DS shfl_xor(32)).
__device__ __forceinline__ float permlane32_min_(float v) {
    int a = __float_as_int(v);
    auto r = __builtin_amdgcn_permlane32_swap(a, a, false, false);
    return fminf(__int_as_float(r[0]), __int_as_float(r[1]));
}

__device__ __forceinline__ float fexp_(float x, float p) {
    float s = (x > 0.f) ? 1.f : ((x < 0.f) ? -1.f : 0.f);
    return s * __powf(fmaxf(fabsf(x), EPS_), p);   // base > 0 -> fast pow safe
}

// ---------------------------------------------------------------------------
// dist_k: block = (bm, 128-n tile). 1280 blocks x 256 (natural occupancy,
// ~100 VGPR — NO launch_bounds second arg: R12 showed it forces
// spill-to-scratch, VGPR 48 + 90 MB scratch traffic, 45 us).
//   In-block staging (fast trig): R, pts[208] w/ |p|^2, rotated n as
//   (A=-2X, |X|^2).
//   Thread: sg=lane&15 owns 13 s (k*16+sg); ng=wave*4+(lane>>4) owns 8 n.
//   Inner loop: 1 ds_read_b128 + 8 evals (add+3fma+min) + 7-min tree; smin
//   partial sm[k] register-resident (compile-time indices).
//   smin reduce: xor16+xor32 via permlane16/32_swap (VALU pipe — R14: the
//   only change vs R13's shfl pair; removes 26 DS ops/wave), then one
//   conflict-free 16-lane LDS atomicMin per k.
//   V epilogue: DPP row butterfly (VALU); row leaders store 8 consecutive
//   V floats straight to vpart (2x float4).
//   Outputs: pure stores. Block 0 zeroes out[] (mid_k accumulates into it).
// ---------------------------------------------------------------------------
__global__ __launch_bounds__(256) void dist_k(
    const float* __restrict__ ipts,  const float* __restrict__ trans,
    const float* __restrict__ rot,   const float* __restrict__ psize,
    const float* __restrict__ shp,   const float* __restrict__ def,
    const float* __restrict__ etas,  const float* __restrict__ omegas,
    float* __restrict__ vpart, float* __restrict__ spart,
    float* __restrict__ out)
{
    __shared__ float4 sPts[PADS_];          // 3328 B
    __shared__ float4 sXt[NT_];             // 2048 B  (A0,A1,A2,c2)
    __shared__ unsigned int sMinS[PADS_];   // 832 B
    __shared__ float sR[9];

    const int t    = threadIdx.x;
    const int tile = blockIdx.x % TILES_;
    const int bm   = blockIdx.x / TILES_;
    const int b    = bm / M_;
    const int lane = t & 63, wave = t >> 6;

    if (blockIdx.x == 0 && t < 4) out[t] = 0.f;   // mid_k accumulates into out

    if (t == 0) {
        float w = rot[bm*4+0], x = rot[bm*4+1], y = rot[bm*4+2], z = rot[bm*4+3];
        float inv = 1.f / sqrtf(w*w + x*x + y*y + z*z);
        w *= inv; x *= inv; y *= inv; z *= inv;
        sR[0] = 1.f - 2.f*(y*y + z*z); sR[1] = 2.f*(x*y - w*z);       sR[2] = 2.f*(x*z + w*y);
        sR[3] = 2.f*(x*y + w*z);       sR[4] = 1.f - 2.f*(x*x + z*z); sR[5] = 2.f*(y*z - w*x);
        sR[6] = 2.f*(x*z - w*y);       sR[7] = 2.f*(y*z + w*x);       sR[8] = 1.f - 2.f*(x*x + y*y);
    }
    if (t < PADS_) {
        sMinS[t] = INF_U;
        if (t < S_) {
            float a1 = psize[bm*3+0], a2 = psize[bm*3+1], a3 = psize[bm*3+2];
            float e1 = shp[bm*2+0],  e2 = shp[bm*2+1];
            float d0 = def[bm*2+0],  d1 = def[bm*2+1];
            float eta = etas[bm*S_+t], om = omegas[bm*S_+t];
            float ce = __cosf(eta), se = __sinf(eta);
            float co = __cosf(om),  so = __sinf(om);
            float fce = fexp_(ce, e1), fse = fexp_(se, e1);
            float fco = fexp_(co, e2), fso = fexp_(so, e2);
            float px = a1 * fce * fco;
            float py = a2 * fce * fso;
            float pz = a3 * fse;
            float fr = pz / a3;
            px *= d0*fr + 1.f;
            py *= d1*fr + 1.f;
            sPts[t] = make_float4(px, py, pz, px*px + py*py + pz*pz);
        } else {
            sPts[t] = make_float4(SENT_, SENT_, SENT_, 3.f*SENT_*SENT_);
        }
    }
    __syncthreads();

    if (t < NT_) {
        int n = tile*NT_ + t;
        const float* ip = ipts + (size_t)(b*N_ + n)*3;
        float cx = ip[0] - trans[bm*3+0];
        float cy = ip[1] - trans[bm*3+1];
        float cz = ip[2] - trans[bm*3+2];
        float X0 = sR[0]*cx + sR[1]*cy + sR[2]*cz;
        float X1 = sR[3]*cx + sR[4]*cy + sR[5]*cz;
        float X2 = sR[6]*cx + sR[7]*cy + sR[8]*cz;
        sXt[t] = make_float4(-2.f*X0, -2.f*X1, -2.f*X2, X0*X0 + X1*X1 + X2*X2);
    }
    __syncthreads();

    const int sg = lane & 15;                // s-group (lane bits 0..3)
    const int ng = wave*4 + (lane >> 4);     // n-group 0..15, owns n = ng*8+j

    float4 A[8];
    #pragma unroll
    for (int j = 0; j < 8; ++j) A[j] = sXt[ng*8 + j];   // broadcast reads

    float vmin[8];
    #pragma unroll
    for (int j = 0; j < 8; ++j) vmin[j] = 3.4e38f;

    float sm[13];                            // smin partials, register-resident

    #pragma unroll
    for (int k = 0; k < 13; ++k) {
        float4 p = sPts[k*16 + sg];          // 2-way bank alias = free
        float d[8];
        #pragma unroll
        for (int j = 0; j < 8; ++j) {
            d[j] = fmaf(p.x, A[j].x,
                   fmaf(p.y, A[j].y,
                   fmaf(p.z, A[j].z, p.w + A[j].w)));
            vmin[j] = fminf(vmin[j], d[j]);
        }
        #pragma unroll
        for (int st = 4; st >= 1; st >>= 1)
            #pragma unroll
            for (int j = 0; j < st; ++j)
                d[j] = fminf(d[j], d[j + st]);
        sm[k] = d[0];
    }

    // smin: reduce over the 16 n-groups — both steps on the VALU pipe
    // (permlane16/32_swap), then one conflict-free 16-lane LDS atomic per k.
    #pragma unroll
    for (int k = 0; k < 13; ++k) {
        float v = sm[k];
        v = permlane16_min_(v);   // xor16
        v = permlane32_min_(v);   // xor32
        if (lane < 16) atomicMin(&sMinS[k*16 + sg], __float_as_uint(v));
    }

    // V: min over the 16 s-groups = DPP row butterfly (VALU pipe, no DS)
    #pragma unroll
    for (int j = 0; j < 8; ++j) {
        float v = vmin[j];
        DPPMIN_(v, 0xB1);   // quad_perm [1,0,3,2]  : xor1
        DPPMIN_(v, 0x4E);   // quad_perm [2,3,0,1]  : xor2
        DPPMIN_(v, 0x141);  // row_half_mirror
        DPPMIN_(v, 0x140);  // row_mirror
        vmin[j] = v;
    }
    if (sg == 0) {                            // row leaders: 8 consecutive V
        float* vp = vpart + bm*N_ + tile*NT_ + ng*8;
        *reinterpret_cast<float4*>(vp)     = make_float4(vmin[0], vmin[1], vmin[2], vmin[3]);
        *reinterpret_cast<float4*>(vp + 4) = make_float4(vmin[4], vmin[5], vmin[6], vmin[7]);
    }

    __syncthreads();                          // sMinS complete
    if (t < S_) spart[(size_t)(bm*TILES_ + tile)*S_ + t] = __uint_as_float(sMinS[t]);
}

// ---------------------------------------------------------------------------
// mid_k: 145 blocks, three roles; all inputs crossed a dispatch boundary.
// Accumulates pre-scaled partials straight into out[] via atomicAdd:
//   bid < 64:          vsort -> out[0], out[1]
//   64 <= bid < 144:   dmp   -> out[0], out[1]
//   bid == 144:        KLD   -> out[0], out[3]
// ---------------------------------------------------------------------------
__global__ __launch_bounds__(256) void mid_k(const float* __restrict__ vpart,
                                             const float* __restrict__ spart,
                                             const float* __restrict__ probs,
                                             const float* __restrict__ mu,
                                             const float* __restrict__ logvar,
                                             float* __restrict__ out)
{
    __shared__ float sSum[4];
    int t = threadIdx.x, lane = t & 63, wave = t >> 6;

    if (blockIdx.x < VS_BLOCKS) {
        int g = blockIdx.x*256 + t;        // 0..B*N-1
        int b = g / N_, n = g % N_;
        float V[M_], P[M_];
        #pragma unroll
        for (int m = 0; m < M_; ++m) {
            V[m] = vpart[(b*M_ + m)*N_ + n];
            P[m] = probs[b*M_ + m];
        }
        #pragma unroll
        for (int i = 0; i < M_-1; ++i)
            #pragma unroll
            for (int j = 0; j < M_-1-i; ++j)
                if (V[j] > V[j+1]) {
                    float tv = V[j]; V[j] = V[j+1]; V[j+1] = tv;
                    float tp = P[j]; P[j] = P[j+1]; P[j+1] = tp;
                }
        float cum = 1.f, sum = 0.f;
        #pragma unroll
        for (int i = 0; i < M_; ++i) { sum += P[i] * cum * V[i]; cum *= (1.f - P[i]); }

        #pragma unroll
        for (int o = 1; o < 64; o <<= 1) sum += __shfl_xor(sum, o);
        if (lane == 0) sSum[wave] = sum;
        __syncthreads();
        if (t == 0) {
            float v = (sSum[0] + sSum[1] + sSum[2] + sSum[3]) / (float)(B_ * N_);
            atomicAdd(&out[0], v);
            atomicAdd(&out[1], v);
        }
    } else if (blockIdx.x < VS_BLOCKS + B_*M_) {
        int bm = blockIdx.x - VS_BLOCKS;   // 0..79
        float v = 0.f;
        if (t < S_) {
            const float* sp = spart + (size_t)bm*TILES_*S_ + t;
            float mn = 3.4e38f;
            #pragma unroll
            for (int tl = 0; tl < TILES_; ++tl) mn = fminf(mn, sp[tl*S_]);
            v = mn;
        }
        #pragma unroll
        for (int o = 1; o < 64; o <<= 1) v += __shfl_xor(v, o);
        if (lane == 0) sSum[wave] = v;
        __syncthreads();
        if (t == 0) {
            float s = (sSum[0] + sSum[1] + sSum[2] + sSum[3]) * probs[bm]
                      / (float)(B_ * S_);
            atomicAdd(&out[0], s);
            atomicAdd(&out[1], s);
        }
    } else {
        float s2 = 0.f;
        for (int i = t; i < B_*L_; i += 256) {
            float muv = mu[i], lv = logvar[i];
            s2 += -0.5f * (1.f + lv - muv*muv - expf(lv));
        }
        #pragma unroll
        for (int o = 1; o < 64; o <<= 1) s2 += __shfl_xor(s2, o);
        if (lane == 0) sSum[wave] = s2;
        __syncthreads();
        if (t == 0) {
            float kld = (sSum[0] + sSum[1] + sSum[2] + sSum[3]) / (float)B_;
            atomicAdd(&out[0], BETA_ * kld);
            atomicAdd(&out[3], kld);
            // out[2] (regs) stays 0 from dist_k's zeroing
        }
    }
}

extern "C" void kernel_launch(void* const* d_in, const int* in_sizes, int n_in,
                              void* d_out, int out_size, void* d_ws, size_t ws_size,
                              hipStream_t stream) {
    const float* ipts    = (const float*)d_in[0];
    const float* trans   = (const float*)d_in[1];
    const float* rot     = (const float*)d_in[2];
    const float* psize   = (const float*)d_in[3];
    const float* shp     = (const float*)d_in[4];
    const float* def     = (const float*)d_in[5];
    const float* probs   = (const float*)d_in[6];
    const float* etas    = (const float*)d_in[7];
    const float* omegas  = (const float*)d_in[8];
    const float* mu      = (const float*)d_in[9];
    const float* logvar  = (const float*)d_in[10];
    float* out = (float*)d_out;

    char* ws = (char*)d_ws;
    float* vpart = (float*)(ws);             // B*M*N*4        = 655360 B
    float* spart = (float*)(ws + 655360);    // B*M*TILES*S*4  = 1024000 B
    // all ws buffers fully written before read (pure stores + dispatch
    // boundary) -> no init needed. out zeroed by dist_k each call.

    dist_k<<<DIST_BLOCKS, 256, 0, stream>>>(ipts, trans, rot, psize, shp, def,
                                            etas, omegas, vpart, spart, out);
    mid_k<<<MID_BLOCKS, 256, 0, stream>>>(vpart, spart, probs, mu, logvar, out);
}

// Round 15
// 25.020 us; speedup vs baseline: 1.4418x; 1.0035x over previous
//
#include <hip/hip_runtime.h>
#include <math.h>

#define B_ 8
#define M_ 10
#define S_ 200
#define PADS_ 208            // S padded to multiple of 16 (sentinel points)
#define N_ 2048
#define L_ 128
#define BETA_ 0.01f
#define EPS_ 1e-6f
#define INF_U 0x7F7F7F7Fu
#define SENT_ 5.0e18f        // sentinel coord; |p|^2 = 7.5e37, finite, never wins min

#define NT_ 128                            // n per block (proven shape)
#define TILES_ (N_ / NT_)                  // 16
#define DIST_BLOCKS (B_ * M_ * TILES_)     // 1280
#define VS_BLOCKS ((B_ * N_) / 256)        // 64
#define MID_BLOCKS (VS_BLOCKS + B_*M_ + 1) // 145

// DPP 16-lane (row) min-reduction step — VALU pipe, no DS ops.
#define DPPMIN_(v, ctrl) \
    v = fminf(v, __int_as_float(__builtin_amdgcn_mov_dpp(__float_as_int(v), ctrl, 0xf, 0xf, true)))

// xor-16 / xor-32 min via permlane swaps (VALU pipe; neutral vs shfl in R14
// but kept — removes DS traffic and proven correct).
__device__ __forceinline__ float permlane16_min_(float v) {
    int a = __float_as_int(v);
    auto r = __builtin_amdgcn_permlane16_swap(a, a, false, false);
    return fminf(__int_as_float(r[0]), __int_as_float(r[1]));
}
__device__ __forceinline__ float permlane32_min_(float v) {
    int a = __float_as_int(v);
    auto r = __builtin_amdgcn_permlane32_swap(a, a, false, false);
    return fminf(__int_as_float(r[0]), __int_as_float(r[1]));
}

__device__ __forceinline__ float fexp_(float x, float p) {
    float s = (x > 0.f) ? 1.f : ((x < 0.f) ? -1.f : 0.f);
    return s * __powf(fmaxf(fabsf(x), EPS_), p);   // base > 0 -> fast pow safe
}

// ---------------------------------------------------------------------------
// dist_k: block = (bm, 128-n tile). 1280 blocks x 256 (natural occupancy —
// NO launch_bounds 2nd arg: R12 proved it spills, VGPR 48 + 90MB scratch).
// R15 restructure: SINGLE staging barrier. Global loads (ipts, etas/omegas)
// issued at kernel entry; quaternion->R computed redundantly in registers on
// every thread (block-uniform s_loads, ~35 VALU) — removes the t==0 serial
// chain + sR LDS round-trip + one barrier, and overlaps both load latencies
// with the trig computation.
//   Thread: sg=lane&15 owns 13 s (k*16+sg); ng=wave*4+(lane>>4) owns 8 n.
//   Inner loop: 1 ds_read_b128 + 8 evals (add+3fma+min) + 7-min tree; smin
//   partial sm[k] register-resident. Post-loop: permlane16/32 + 16-lane
//   conflict-free LDS atomicMin per k. V epilogue: DPP row butterfly.
//   Outputs: pure stores. Block 0 zeroes out[] (mid_k accumulates into it).
// ---------------------------------------------------------------------------
__global__ __launch_bounds__(256) void dist_k(
    const float* __restrict__ ipts,  const float* __restrict__ trans,
    const float* __restrict__ rot,   const float* __restrict__ psize,
    const float* __restrict__ shp,   const float* __restrict__ def,
    const float* __restrict__ etas,  const float* __restrict__ omegas,
    float* __restrict__ vpart, float* __restrict__ spart,
    float* __restrict__ out)
{
    __shared__ float4 sPts[PADS_];          // 3328 B
    __shared__ float4 sXt[NT_];             // 2048 B  (A0,A1,A2,c2)
    __shared__ unsigned int sMinS[PADS_];   // 832 B

    const int t    = threadIdx.x;
    const int tile = blockIdx.x % TILES_;
    const int bm   = blockIdx.x / TILES_;
    const int b    = bm / M_;
    const int lane = t & 63, wave = t >> 6;

    if (blockIdx.x == 0 && t < 4) out[t] = 0.f;   // mid_k accumulates into out

    // ---- issue global loads FIRST (latency overlaps the register work) ----
    float ipx = 0.f, ipy = 0.f, ipz = 0.f;
    if (t < NT_) {
        const float* ip = ipts + (size_t)(b*N_ + tile*NT_ + t)*3;
        ipx = ip[0]; ipy = ip[1]; ipz = ip[2];
    }
    float eta = 0.f, om = 0.f;
    if (t < S_) { eta = etas[bm*S_+t]; om = omegas[bm*S_+t]; }

    // ---- quaternion -> R in registers, ALL threads (no t==0 serial chain,
    //      no LDS round-trip; rot/trans are block-uniform -> scalar loads) ----
    float qw = rot[bm*4+0], qx = rot[bm*4+1], qy = rot[bm*4+2], qz = rot[bm*4+3];
    float inv = 1.f / sqrtf(qw*qw + qx*qx + qy*qy + qz*qz);
    qw *= inv; qx *= inv; qy *= inv; qz *= inv;
    const float r00 = 1.f - 2.f*(qy*qy + qz*qz), r01 = 2.f*(qx*qy - qw*qz), r02 = 2.f*(qx*qz + qw*qy);
    const float r10 = 2.f*(qx*qy + qw*qz), r11 = 1.f - 2.f*(qx*qx + qz*qz), r12 = 2.f*(qy*qz - qw*qx);
    const float r20 = 2.f*(qx*qz - qw*qy), r21 = 2.f*(qy*qz + qw*qx), r22 = 1.f - 2.f*(qx*qx + qy*qy);

    // ---- stage pts (trig) + sMinS init ----
    if (t < PADS_) {
        sMinS[t] = INF_U;
        if (t < S_) {
            float a1 = psize[bm*3+0], a2 = psize[bm*3+1], a3 = psize[bm*3+2];
            float e1 = shp[bm*2+0],  e2 = shp[bm*2+1];
            float d0 = def[bm*2+0],  d1 = def[bm*2+1];
            float ce = __cosf(eta), se = __sinf(eta);
            float co = __cosf(om),  so = __sinf(om);
            float fce = fexp_(ce, e1), fse = fexp_(se, e1);
            float fco = fexp_(co, e2), fso = fexp_(so, e2);
            float px = a1 * fce * fco;
            float py = a2 * fce * fso;
            float pz = a3 * fse;
            float fr = pz / a3;
            px *= d0*fr + 1.f;
            py *= d1*fr + 1.f;
            sPts[t] = make_float4(px, py, pz, px*px + py*py + pz*pz);
        } else {
            sPts[t] = make_float4(SENT_, SENT_, SENT_, 3.f*SENT_*SENT_);
        }
    }

    // ---- stage rotated n-points (R in regs, ipts already in regs) ----
    if (t < NT_) {
        float cx = ipx - trans[bm*3+0];
        float cy = ipy - trans[bm*3+1];
        float cz = ipz - trans[bm*3+2];
        float X0 = r00*cx + r01*cy + r02*cz;
        float X1 = r10*cx + r11*cy + r12*cz;
        float X2 = r20*cx + r21*cy + r22*cz;
        sXt[t] = make_float4(-2.f*X0, -2.f*X1, -2.f*X2, X0*X0 + X1*X1 + X2*X2);
    }
    __syncthreads();                         // single staging barrier

    const int sg = lane & 15;                // s-group (lane bits 0..3)
    const int ng = wave*4 + (lane >> 4);     // n-group 0..15, owns n = ng*8+j

    float4 A[8];
    #pragma unroll
    for (int j = 0; j < 8; ++j) A[j] = sXt[ng*8 + j];   // broadcast reads

    float vmin[8];
    #pragma unroll
    for (int j = 0; j < 8; ++j) vmin[j] = 3.4e38f;

    float sm[13];                            // smin partials, register-resident

    #pragma unroll
    for (int k = 0; k < 13; ++k) {
        float4 p = sPts[k*16 + sg];          // 2-way bank alias = free
        float d[8];
        #pragma unroll
        for (int j = 0; j < 8; ++j) {
            d[j] = fmaf(p.x, A[j].x,
                   fmaf(p.y, A[j].y,
                   fmaf(p.z, A[j].z, p.w + A[j].w)));
            vmin[j] = fminf(vmin[j], d[j]);
        }
        #pragma unroll
        for (int st = 4; st >= 1; st >>= 1)
            #pragma unroll
            for (int j = 0; j < st; ++j)
                d[j] = fminf(d[j], d[j + st]);
        sm[k] = d[0];
    }

    // smin: reduce over the 16 n-groups (VALU permlanes), one conflict-free
    // 16-lane LDS atomic per k.
    #pragma unroll
    for (int k = 0; k < 13; ++k) {
        float v = sm[k];
        v = permlane16_min_(v);   // xor16
        v = permlane32_min_(v);   // xor32
        if (lane < 16) atomicMin(&sMinS[k*16 + sg], __float_as_uint(v));
    }

    // V: min over the 16 s-groups = DPP row butterfly (VALU pipe, no DS)
    #pragma unroll
    for (int j = 0; j < 8; ++j) {
        float v = vmin[j];
        DPPMIN_(v, 0xB1);   // quad_perm [1,0,3,2]  : xor1
        DPPMIN_(v, 0x4E);   // quad_perm [2,3,0,1]  : xor2
        DPPMIN_(v, 0x141);  // row_half_mirror
        DPPMIN_(v, 0x140);  // row_mirror
        vmin[j] = v;
    }
    if (sg == 0) {                            // row leaders: 8 consecutive V
        float* vp = vpart + bm*N_ + tile*NT_ + ng*8;
        *reinterpret_cast<float4*>(vp)     = make_float4(vmin[0], vmin[1], vmin[2], vmin[3]);
        *reinterpret_cast<float4*>(vp + 4) = make_float4(vmin[4], vmin[5], vmin[6], vmin[7]);
    }

    __syncthreads();                          // sMinS complete
    if (t < S_) spart[(size_t)(bm*TILES_ + tile)*S_ + t] = __uint_as_float(sMinS[t]);
}

// ---------------------------------------------------------------------------
// mid_k: 145 blocks, three roles; all inputs crossed a dispatch boundary.
// Accumulates pre-scaled partials straight into out[] via atomicAdd:
//   bid < 64:          vsort -> out[0], out[1]
//   64 <= bid < 144:   dmp   -> out[0], out[1]
//   bid == 144:        KLD   -> out[0], out[3]
// ---------------------------------------------------------------------------
__global__ __launch_bounds__(256) void mid_k(const float* __restrict__ vpart,
                                             const float* __restrict__ spart,
                                             const float* __restrict__ probs,
                                             const float* __restrict__ mu,
                                             const float* __restrict__ logvar,
                                             float* __restrict__ out)
{
    __shared__ float sSum[4];
    int t = threadIdx.x, lane = t & 63, wave = t >> 6;

    if (blockIdx.x < VS_BLOCKS) {
        int g = blockIdx.x*256 + t;        // 0..B*N-1
        int b = g / N_, n = g % N_;
        float V[M_], P[M_];
        #pragma unroll
        for (int m = 0; m < M_; ++m) {
            V[m] = vpart[(b*M_ + m)*N_ + n];
            P[m] = probs[b*M_ + m];
        }
        #pragma unroll
        for (int i = 0; i < M_-1; ++i)
            #pragma unroll
            for (int j = 0; j < M_-1-i; ++j)
                if (V[j] > V[j+1]) {
                    float tv = V[j]; V[j] = V[j+1]; V[j+1] = tv;
                    float tp = P[j]; P[j] = P[j+1]; P[j+1] = tp;
                }
        float cum = 1.f, sum = 0.f;
        #pragma unroll
        for (int i = 0; i < M_; ++i) { sum += P[i] * cum * V[i]; cum *= (1.f - P[i]); }

        #pragma unroll
        for (int o = 1; o < 64; o <<= 1) sum += __shfl_xor(sum, o);
        if (lane == 0) sSum[wave] = sum;
        __syncthreads();
        if (t == 0) {
            float v = (sSum[0] + sSum[1] + sSum[2] + sSum[3]) / (float)(B_ * N_);
            atomicAdd(&out[0], v);
            atomicAdd(&out[1], v);
        }
    } else if (blockIdx.x < VS_BLOCKS + B_*M_) {
        int bm = blockIdx.x - VS_BLOCKS;   // 0..79
        float v = 0.f;
        if (t < S_) {
            const float* sp = spart + (size_t)bm*TILES_*S_ + t;
            float mn = 3.4e38f;
            #pragma unroll
            for (int tl = 0; tl < TILES_; ++tl) mn = fminf(mn, sp[tl*S_]);
            v = mn;
        }
        #pragma unroll
        for (int o = 1; o < 64; o <<= 1) v += __shfl_xor(v, o);
        if (lane == 0) sSum[wave] = v;
        __syncthreads();
        if (t == 0) {
            float s = (sSum[0] + sSum[1] + sSum[2] + sSum[3]) * probs[bm]
                      / (float)(B_ * S_);
            atomicAdd(&out[0], s);
            atomicAdd(&out[1], s);
        }
    } else {
        float s2 = 0.f;
        for (int i = t; i < B_*L_; i += 256) {
            float muv = mu[i], lv = logvar[i];
            s2 += -0.5f * (1.f + lv - muv*muv - expf(lv));
        }
        #pragma unroll
        for (int o = 1; o < 64; o <<= 1) s2 += __shfl_xor(s2, o);
        if (lane == 0) sSum[wave] = s2;
        __syncthreads();
        if (t == 0) {
            float kld = (sSum[0] + sSum[1] + sSum[2] + sSum[3]) / (float)B_;
            atomicAdd(&out[0], BETA_ * kld);
            atomicAdd(&out[3], kld);
            // out[2] (regs) stays 0 from dist_k's zeroing
        }
    }
}

extern "C" void kernel_launch(void* const* d_in, const int* in_sizes, int n_in,
                              void* d_out, int out_size, void* d_ws, size_t ws_size,
                              hipStream_t stream) {
    const float* ipts    = (const float*)d_in[0];
    const float* trans   = (const float*)d_in[1];
    const float* rot     = (const float*)d_in[2];
    const float* psize   = (const float*)d_in[3];
    const float* shp     = (const float*)d_in[4];
    const float* def     = (const float*)d_in[5];
    const float* probs   = (const float*)d_in[6];
    const float* etas    = (const float*)d_in[7];
    const float* omegas  = (const float*)d_in[8];
    const float* mu      = (const float*)d_in[9];
    const float* logvar  = (const float*)d_in[10];
    float* out = (float*)d_out;

    char* ws = (char*)d_ws;
    float* vpart = (float*)(ws);             // B*M*N*4        = 655360 B
    float* spart = (float*)(ws + 655360);    // B*M*TILES*S*4  = 1024000 B
    // all ws buffers fully written before read (pure stores + dispatch
    // boundary) -> no init needed. out zeroed by dist_k each call.

    dist_k<<<DIST_BLOCKS, 256, 0, stream>>>(ipts, trans, rot, psize, shp, def,
                                            etas, omegas, vpart, spart, out);
    mid_k<<<MID_BLOCKS, 256, 0, stream>>>(vpart, spart, probs, mu, logvar, out);
}